// Round 5
// baseline (263.663 us; speedup 1.0000x reference)
//
#include <hip/hip_runtime.h>
#include <hip/hip_bf16.h>

typedef __attribute__((ext_vector_type(8))) short short8;
typedef __attribute__((ext_vector_type(4))) float floatx4;
typedef _Float16 half2v __attribute__((ext_vector_type(2)));

// flag==1: inputs fp32 (proven R2->R3); flag==0: bf16.
__device__ __forceinline__ float ld_f(const void* p, int f32, int i) {
  if (f32) return ((const float*)p)[i];
  unsigned short u = ((const unsigned short*)p)[i];
  return __uint_as_float(((unsigned)u) << 16);
}
__device__ __forceinline__ short ld_bf(const void* p, int f32, int i) {
  if (!f32) return ((const short*)p)[i];
  __hip_bfloat16 h = __float2bfloat16(((const float*)p)[i]);
  return *reinterpret_cast<short*>(&h);
}
__device__ __forceinline__ unsigned short f_to_bfu(float v) {
  __hip_bfloat16 h = __float2bfloat16(v);
  return *reinterpret_cast<unsigned short*>(&h);
}
__device__ __forceinline__ short f_to_h(float v) {
  _Float16 h = (_Float16)v;
  return *reinterpret_cast<short*>(&h);
}
__device__ __forceinline__ float bflo(unsigned w) { return __uint_as_float(w << 16); }
__device__ __forceinline__ float bfhi(unsigned w) { return __uint_as_float(w & 0xFFFF0000u); }

// init: block 0 detects dtype; remaining blocks zero cnt.
__global__ void init_kernel(const unsigned short* __restrict__ xs, int* __restrict__ flag,
                            int* __restrict__ cnt, int N) {
  if (blockIdx.x == 0) {
    __shared__ int sbad;
    if (threadIdx.x == 0) sbad = 0;
    __syncthreads();
    int bad = 0;
    for (int j = 2 * threadIdx.x; j < 16384; j += 512) {  // EVEN u16 slots
      unsigned e = (xs[j] >> 7) & 0xFF;
      if (e >= 0xF0) bad = 1;
    }
    if (bad) atomicOr(&sbad, 1);
    __syncthreads();
    if (threadIdx.x == 0) flag[0] = sbad;
    return;
  }
  int i = (blockIdx.x - 1) * blockDim.x + threadIdx.x;
  if (i < N) cnt[i] = 0;
}

// prep (43 blocks: biases + weight packs) fused with hist (rest).
// hist records each edge's rank within its target (atomic return value),
// so the later CSR fill needs no atomics at all.
__global__ void prep_hist(const void* bg, const void* bq, const void* bk, const void* bv,
                          const void* bs, const void* Wg, const void* Wq, const void* Wk,
                          const void* Wv, const void* Ws, const int* __restrict__ flag,
                          float* __restrict__ bgf, float* __restrict__ bias512,
                          short* __restrict__ WpG, short* __restrict__ WpQ,
                          const int* __restrict__ ei, int* __restrict__ cnt,
                          int* __restrict__ erank, int E, int Gp) {
  if ((int)blockIdx.x >= Gp) {
    int e = (blockIdx.x - Gp) * blockDim.x + threadIdx.x;
    if (e < E) erank[e] = atomicAdd(&cnt[ei[E + e]], 1);
    return;
  }
  int tid = blockIdx.x * blockDim.x + threadIdx.x;
  int f = *flag;
  if (tid < 128) { bgf[tid] = ld_f(bg, f, tid); return; }
  if (tid < 640) {
    int t = tid - 128;
    const void* b = (t < 128) ? bq : (t < 256) ? bk : (t < 384) ? bv : bs;
    bias512[t] = ld_f(b, f, t & 127);
    return;
  }
  if (tid < 640 + 2048) {  // pack W_gcn
    int id = tid - 640;
    int lane = id & 63, kb = (id >> 6) & 3, tn = id >> 8;
    int k0 = kb * 32 + (lane >> 4) * 8;
    int n = tn * 16 + (lane & 15);
    short* dst = WpG + (size_t)id * 8;
#pragma unroll
    for (int j = 0; j < 8; ++j) dst[j] = ld_bf(Wg, f, (k0 + j) * 128 + n);
    return;
  }
  if (tid < 640 + 2048 + 8192) {  // pack Wq|Wk|Wv|Ws
    int id = tid - 640 - 2048;
    int lane = id & 63, kb = (id >> 6) & 3, tn = id >> 8;
    int k0 = kb * 32 + (lane >> 4) * 8;
    int n = tn * 16 + (lane & 15);
    const void* W = (n < 128) ? Wq : (n < 256) ? Wk : (n < 384) ? Wv : Ws;
    int col = n & 127;
    short* dst = WpQ + (size_t)id * 8;
#pragma unroll
    for (int j = 0; j < 8; ++j) dst[j] = ld_bf(W, f, (k0 + j) * 128 + col);
  }
}

__global__ void scanA(const int* __restrict__ cnt, int* __restrict__ chunkscan,
                      int* __restrict__ partials, int N) {
  __shared__ int sh[1024];
  int t = threadIdx.x;
  int g = blockIdx.x * 1024 + t;
  int v = (g < N) ? cnt[g] : 0;
  sh[t] = v;
  __syncthreads();
  for (int o = 1; o < 1024; o <<= 1) {
    int add = (t >= o) ? sh[t - o] : 0;
    __syncthreads();
    sh[t] += add;
    __syncthreads();
  }
  if (g < N) chunkscan[g] = sh[t];
  if (t == 1023) partials[blockIdx.x] = sh[1023];
}

// wave-parallel exclusive scan over partials (nb <= 64 fast path)
__global__ void scanB(int* __restrict__ partials, int nb) {
  int lane = threadIdx.x;
  if (nb <= 64) {
    int v = (lane < nb) ? partials[lane] : 0;
#pragma unroll
    for (int o = 1; o < 64; o <<= 1) {
      int t = __shfl_up(v, o);
      if (lane >= o) v += t;
    }
    int ex = __shfl_up(v, 1);
    if (lane == 0) ex = 0;
    if (lane < nb) partials[lane] = ex;
    return;
  }
  if (lane == 0) {
    int run = 0;
    for (int b = 0; b < nb; ++b) {
      int t = partials[b];
      partials[b] = run;
      run += t;
    }
  }
}

// rowptr + dinv fused
__global__ void scanC(const int* __restrict__ cnt, const int* __restrict__ chunkscan,
                      const int* __restrict__ partials, int* __restrict__ rowptr,
                      float* __restrict__ dinv, int N) {
  int g = blockIdx.x * blockDim.x + threadIdx.x;
  if (g == 0) rowptr[0] = 0;
  if (g >= N) return;
  int c = cnt[g];
  int inc = chunkscan[g] + partials[g >> 10];
  rowptr[g + 1] = inc;
  dinv[g] = rsqrtf((float)c + 1.0f);  // +1 self-loop
}

// ---- fused: MFMA GEMM h0' = (x @ W_gcn)*dinv[row] (bf16, pre-scaled) + CSR fill ----
// Fill is atomic-free: pos = rowptr[t] + erank[e] (rank captured during histogram).
__global__ void gemmh0_fill(const void* __restrict__ X, const int* __restrict__ flag,
                            const short* __restrict__ Bp, const float* __restrict__ dinv,
                            short* __restrict__ C, int M, const int* __restrict__ ei,
                            const int* __restrict__ rowptr, const int* __restrict__ erank,
                            int* __restrict__ srcs, int E, int Gg) {
  if ((int)blockIdx.x >= Gg) {
    int e = (blockIdx.x - Gg) * blockDim.x + threadIdx.x;
    if (e < E) {
      int t = ei[E + e];
      srcs[rowptr[t] + erank[e]] = ei[e];
    }
    return;
  }
  int wv = (blockIdx.x * blockDim.x + threadIdx.x) >> 6;
  int lane = threadIdx.x & 63;
  int tilesM = (M + 15) >> 4;
  if (wv >= tilesM) return;
  int f = *flag;
  int tm = wv;
  int m = tm * 16 + (lane & 15);
  int mc = m < M ? m : M - 1;
  int quad = lane >> 4;
  short8 a[4];
  if (f) {
    const float4* xr = (const float4*)((const float*)X + (size_t)mc * 128) + quad * 2;
#pragma unroll
    for (int kb = 0; kb < 4; ++kb) {
      float4 u = xr[kb * 8];
      float4 w = xr[kb * 8 + 1];
      a[kb][0] = (short)f_to_bfu(u.x);
      a[kb][1] = (short)f_to_bfu(u.y);
      a[kb][2] = (short)f_to_bfu(u.z);
      a[kb][3] = (short)f_to_bfu(u.w);
      a[kb][4] = (short)f_to_bfu(w.x);
      a[kb][5] = (short)f_to_bfu(w.y);
      a[kb][6] = (short)f_to_bfu(w.z);
      a[kb][7] = (short)f_to_bfu(w.w);
    }
  } else {
    const short* xr = (const short*)X + (size_t)mc * 128 + quad * 8;
#pragma unroll
    for (int kb = 0; kb < 4; ++kb) a[kb] = *(const short8*)(xr + kb * 32);
  }
  floatx4 acc[8];
#pragma unroll
  for (int tn = 0; tn < 8; ++tn) acc[tn] = (floatx4){0.f, 0.f, 0.f, 0.f};
#pragma unroll
  for (int kb = 0; kb < 4; ++kb) {
#pragma unroll
    for (int tn = 0; tn < 8; ++tn) {
      short8 b8 = *(const short8*)(Bp + ((size_t)(tn * 4 + kb) * 64 + lane) * 8);
      acc[tn] = __builtin_amdgcn_mfma_f32_16x16x32_bf16(a[kb], b8, acc[tn], 0, 0, 0);
    }
  }
  int row0 = tm * 16 + quad * 4;
  int cl = lane & 15;
  float dsc[4];
#pragma unroll
  for (int r = 0; r < 4; ++r) dsc[r] = (row0 + r < M) ? dinv[row0 + r] : 0.f;
#pragma unroll
  for (int tn = 0; tn < 8; ++tn)
#pragma unroll
    for (int r = 0; r < 4; ++r)
      if (row0 + r < M)
        C[(size_t)(row0 + r) * 128 + tn * 16 + cl] = (short)f_to_bfu(acc[tn][r] * dsc[r]);
}

// ---- GCN aggregation on pre-scaled h0': h = relu(dt*(sum h0'[s] + h0'[t]) + bg) ----
// 2 nodes/wave: each 32-lane half owns one node; within a half, 2 quarters cover the
// 256B h0 row (16 lanes x 16B) and stagger edge slots. Neighbor list register-cached
// (32 edges/half); predicated unroll-4 (slots = base+q2, +2, +4, +6); tail only for
// deg>32 (P~1e-7). One combine level (xor16) instead of two.
__global__ void gcn_gather(const int* __restrict__ rowptr, const int* __restrict__ srcs,
                           const float* __restrict__ dinv, const unsigned* __restrict__ h0,
                           const float* __restrict__ bgf, unsigned* __restrict__ hbf, int N) {
  int wv = (int)((blockIdx.x * (long long)blockDim.x + threadIdx.x) >> 6);
  int lane = threadIdx.x & 63;
  int hf = lane >> 5, q2 = (lane >> 4) & 1, sl = lane & 15, sl32 = lane & 31;
  int node = wv * 2 + hf;
  int nodec = node < N ? node : N - 1;
  int beg = rowptr[nodec], end = rowptr[nodec + 1];
  int deg = node < N ? end - beg : 0;
  int dm1 = deg - 1;
  int dmc = dm1 > 0 ? dm1 : 0;
  int sreg = srcs[deg > 0 ? beg + (sl32 < dm1 ? sl32 : dm1) : 0];
  int degmax = deg;
  degmax = max(degmax, __shfl_xor(degmax, 32));
  int dd = degmax < 32 ? degmax : 32;
  int hb = hf << 5;
  float a0 = 0.f, a1 = 0.f, a2 = 0.f, a3 = 0.f, a4 = 0.f, a5 = 0.f, a6 = 0.f, a7 = 0.f;
  for (int base = 0; base < dd; base += 8) {
    int p0 = base + q2, p1 = p0 + 2, p2 = p0 + 4, p3 = p0 + 6;
    int s0 = __shfl(sreg, hb + (p0 < dmc ? p0 : dmc));
    int s1 = __shfl(sreg, hb + (p1 < dmc ? p1 : dmc));
    int s2 = __shfl(sreg, hb + (p2 < dmc ? p2 : dmc));
    int s3 = __shfl(sreg, hb + (p3 < dmc ? p3 : dmc));
    float m0 = p0 < deg ? 1.f : 0.f;
    float m1 = p1 < deg ? 1.f : 0.f;
    float m2 = p2 < deg ? 1.f : 0.f;
    float m3 = p3 < deg ? 1.f : 0.f;
    uint4 w0 = *(const uint4*)(h0 + (size_t)s0 * 64 + sl * 4);
    uint4 w1 = *(const uint4*)(h0 + (size_t)s1 * 64 + sl * 4);
    uint4 w2 = *(const uint4*)(h0 + (size_t)s2 * 64 + sl * 4);
    uint4 w3 = *(const uint4*)(h0 + (size_t)s3 * 64 + sl * 4);
    a0 += m0 * bflo(w0.x) + m1 * bflo(w1.x) + m2 * bflo(w2.x) + m3 * bflo(w3.x);
    a1 += m0 * bfhi(w0.x) + m1 * bfhi(w1.x) + m2 * bfhi(w2.x) + m3 * bfhi(w3.x);
    a2 += m0 * bflo(w0.y) + m1 * bflo(w1.y) + m2 * bflo(w2.y) + m3 * bflo(w3.y);
    a3 += m0 * bfhi(w0.y) + m1 * bfhi(w1.y) + m2 * bfhi(w2.y) + m3 * bfhi(w3.y);
    a4 += m0 * bflo(w0.z) + m1 * bflo(w1.z) + m2 * bflo(w2.z) + m3 * bflo(w3.z);
    a5 += m0 * bfhi(w0.z) + m1 * bfhi(w1.z) + m2 * bfhi(w2.z) + m3 * bfhi(w3.z);
    a6 += m0 * bflo(w0.w) + m1 * bflo(w1.w) + m2 * bflo(w2.w) + m3 * bflo(w3.w);
    a7 += m0 * bfhi(w0.w) + m1 * bfhi(w1.w) + m2 * bfhi(w2.w) + m3 * bfhi(w3.w);
  }
  for (int i = beg + 32 + q2; i < end; i += 2) {  // deg > 32: essentially never
    uint4 w0 = *(const uint4*)(h0 + (size_t)srcs[i] * 64 + sl * 4);
    a0 += bflo(w0.x);
    a1 += bfhi(w0.x);
    a2 += bflo(w0.y);
    a3 += bfhi(w0.y);
    a4 += bflo(w0.z);
    a5 += bfhi(w0.z);
    a6 += bflo(w0.w);
    a7 += bfhi(w0.w);
  }
  // combine the 2 quarters of this half
  a0 += __shfl_xor(a0, 16);
  a1 += __shfl_xor(a1, 16);
  a2 += __shfl_xor(a2, 16);
  a3 += __shfl_xor(a3, 16);
  a4 += __shfl_xor(a4, 16);
  a5 += __shfl_xor(a5, 16);
  a6 += __shfl_xor(a6, 16);
  a7 += __shfl_xor(a7, 16);
  if (q2 == 0 && node < N) {
    uint4 hw = *(const uint4*)(h0 + (size_t)node * 64 + sl * 4);
    float dt = dinv[node];
    const float4* bb = (const float4*)bgf;
    float4 b0 = bb[sl * 2], b1 = bb[sl * 2 + 1];
    float v0 = (a0 + bflo(hw.x)) * dt + b0.x;
    float v1 = (a1 + bfhi(hw.x)) * dt + b0.y;
    float v2 = (a2 + bflo(hw.y)) * dt + b0.z;
    float v3 = (a3 + bfhi(hw.y)) * dt + b0.w;
    float v4 = (a4 + bflo(hw.z)) * dt + b1.x;
    float v5 = (a5 + bfhi(hw.z)) * dt + b1.y;
    float v6 = (a6 + bflo(hw.w)) * dt + b1.z;
    float v7 = (a7 + bfhi(hw.w)) * dt + b1.w;
    v0 = v0 > 0.f ? v0 : 0.f;
    v1 = v1 > 0.f ? v1 : 0.f;
    v2 = v2 > 0.f ? v2 : 0.f;
    v3 = v3 > 0.f ? v3 : 0.f;
    v4 = v4 > 0.f ? v4 : 0.f;
    v5 = v5 > 0.f ? v5 : 0.f;
    v6 = v6 > 0.f ? v6 : 0.f;
    v7 = v7 > 0.f ? v7 : 0.f;
    uint4 o;
    o.x = (unsigned)f_to_bfu(v0) | ((unsigned)f_to_bfu(v1) << 16);
    o.y = (unsigned)f_to_bfu(v2) | ((unsigned)f_to_bfu(v3) << 16);
    o.z = (unsigned)f_to_bfu(v4) | ((unsigned)f_to_bfu(v5) << 16);
    o.w = (unsigned)f_to_bfu(v6) | ((unsigned)f_to_bfu(v7) << 16);
    *(uint4*)(hbf + (size_t)node * 64 + sl * 4) = o;
  }
}

// ---- MFMA GEMM [q|k|v|s] = h @ Wp + bias. q stored f16; k/v interleaved in kvb
// (per node row 512B: lane chunk l = [4x f16 k | 4x bf16 v] for channels 4l..4l+3);
// skip bf16. Wave = 16 rows x one 128-col group (acc[8], no spill).
__global__ void gemm_qkvs(const short* __restrict__ A, const short* __restrict__ Bp,
                          const float* __restrict__ bias512, short* __restrict__ qb,
                          short* __restrict__ kvb, short* __restrict__ skipb, int M) {
  int wv = (blockIdx.x * blockDim.x + threadIdx.x) >> 6;
  int lane = threadIdx.x & 63;
  int tilesM = (M + 15) >> 4;
  if (wv >= tilesM * 4) return;
  int tng = wv & 3, tm = wv >> 2;
  int m = tm * 16 + (lane & 15);
  int mc = m < M ? m : M - 1;
  int quad = lane >> 4;
  const short* Arow = A + (size_t)mc * 128 + quad * 8;
  short8 a[4];
#pragma unroll
  for (int kb = 0; kb < 4; ++kb) a[kb] = *(const short8*)(Arow + kb * 32);
  floatx4 acc[8];
#pragma unroll
  for (int j = 0; j < 8; ++j) acc[j] = (floatx4){0.f, 0.f, 0.f, 0.f};
#pragma unroll
  for (int kb = 0; kb < 4; ++kb) {
#pragma unroll
    for (int j = 0; j < 8; ++j) {
      int tn = tng * 8 + j;
      short8 b8 = *(const short8*)(Bp + ((size_t)(tn * 4 + kb) * 64 + lane) * 8);
      acc[j] = __builtin_amdgcn_mfma_f32_16x16x32_bf16(a[kb], b8, acc[j], 0, 0, 0);
    }
  }
  int row0 = tm * 16 + quad * 4;
  int cl = lane & 15;
#pragma unroll
  for (int j = 0; j < 8; ++j) {
    int cc = j * 16 + cl;
    float b = bias512[tng * 128 + cc];
#pragma unroll
    for (int r = 0; r < 4; ++r) {
      int row = row0 + r;
      if (row >= M) continue;
      float val = acc[j][r] + b;
      if (tng == 0) {
        qb[(size_t)row * 128 + cc] = f_to_h(val);
      } else if (tng == 3) {
        skipb[(size_t)row * 128 + cc] = (short)f_to_bfu(val);
      } else {
        size_t base = (size_t)row * 256 + (size_t)((cc >> 2) * 8 + (cc & 3));
        if (tng == 1)
          kvb[base] = f_to_h(val);          // k: f16
        else
          kvb[base + 4] = (short)f_to_bfu(val);  // v: bf16
      }
    }
  }
}

// ---- Fused attention: no-max softmax (dots ~N(0,1), exp-safe), f16 dot ----
// One node per wave (max wave-level parallelism); the 2 halves stagger slots
// (even/odd). Burst-8: 8 load instructions issued back-to-back = 16 edges in
// flight per wave before any dependent compute. Dot reduce is pure-VALU DPP.
__device__ __forceinline__ float dpp_red8(float p) {
  p += __int_as_float(__builtin_amdgcn_mov_dpp(__float_as_int(p), 0xB1, 0xF, 0xF, true));
  p += __int_as_float(__builtin_amdgcn_mov_dpp(__float_as_int(p), 0x4E, 0xF, 0xF, true));
  p += __int_as_float(__builtin_amdgcn_mov_dpp(__float_as_int(p), 0x141, 0xF, 0xF, true));
  return p;
}
__device__ __forceinline__ float dot_dpp(half2v qa, half2v qc, unsigned kw0, unsigned kw1) {
  half2v k0 = *reinterpret_cast<half2v*>(&kw0);
  half2v k1 = *reinterpret_cast<half2v*>(&kw1);
#if __has_builtin(__builtin_amdgcn_fdot2)
  float p = __builtin_amdgcn_fdot2(qa, k0, 0.f, false);
  p = __builtin_amdgcn_fdot2(qc, k1, p, false);
#else
  float p = (float)qa[0] * (float)k0[0] + (float)qa[1] * (float)k0[1] +
            (float)qc[0] * (float)k1[0] + (float)qc[1] * (float)k1[1];
#endif
  return dpp_red8(p) * 0.17677669529663687f;  // 1/sqrt(32)
}

__global__ void attn_fused(const int* __restrict__ rowptr, const int* __restrict__ srcs,
                           const unsigned* __restrict__ qb, const unsigned* __restrict__ kvb,
                           const unsigned* __restrict__ skipb, float* __restrict__ out, int N) {
  int node = (int)((blockIdx.x * (long long)blockDim.x + threadIdx.x) >> 6);
  if (node >= N) return;
  int lane = threadIdx.x & 63;
  int hf = lane >> 5, sl = lane & 31;
  uint2 qw = *(const uint2*)(qb + (size_t)node * 64 + sl * 2);
  half2v qa = *reinterpret_cast<half2v*>(&qw.x);
  half2v qc = *reinterpret_cast<half2v*>(&qw.y);
  int beg = rowptr[node], end = rowptr[node + 1];
  int deg = end - beg;
  int dm1 = deg - 1;
  int dmc = dm1 > 0 ? dm1 : 0;
  int sreg = srcs[deg > 0 ? beg + (lane < dm1 ? lane : dm1) : 0];
  int dd = deg < 64 ? deg : 64;

  float denom = 0.f, ax0 = 0.f, ax1 = 0.f, ax2 = 0.f, ax3 = 0.f;
  for (int base = 0; base < dd; base += 16) {
    uint4 kv[8];
    int pp[8];
#pragma unroll
    for (int j = 0; j < 8; ++j) {
      int p = base + hf + 2 * j;  // half 0: even slots, half 1: odd slots
      pp[j] = p;
      int s = __shfl(sreg, p < dmc ? p : dmc);
      kv[j] = *(const uint4*)(kvb + (size_t)s * 128 + sl * 4);
    }
#pragma unroll
    for (int j = 0; j < 8; ++j) {
      float e = __expf(dot_dpp(qa, qc, kv[j].x, kv[j].y));
      e = pp[j] < deg ? e : 0.f;
      denom += e;
      ax0 += e * bflo(kv[j].z);
      ax1 += e * bfhi(kv[j].z);
      ax2 += e * bflo(kv[j].w);
      ax3 += e * bfhi(kv[j].w);
    }
  }
  for (int i = beg + 64 + hf; i < end; i += 2) {  // deg > 64: essentially never
    int s0 = srcs[i];
    uint4 kv0 = *(const uint4*)(kvb + (size_t)s0 * 128 + sl * 4);
    float e0 = __expf(dot_dpp(qa, qc, kv0.x, kv0.y));
    denom += e0;
    ax0 += e0 * bflo(kv0.z);
    ax1 += e0 * bfhi(kv0.z);
    ax2 += e0 * bflo(kv0.w);
    ax3 += e0 * bfhi(kv0.w);
  }
  // combine the two halves (all lanes active)
  denom += __shfl_xor(denom, 32);
  ax0 += __shfl_xor(ax0, 32);
  ax1 += __shfl_xor(ax1, 32);
  ax2 += __shfl_xor(ax2, 32);
  ax3 += __shfl_xor(ax3, 32);
  if (hf == 0) {
    float r = denom > 0.f ? 1.f / denom : 0.f;
    uint2 sw = *(const uint2*)(skipb + (size_t)node * 64 + sl * 2);
    float4 o;
    o.x = ax0 * r + bflo(sw.x);
    o.y = ax1 * r + bfhi(sw.x);
    o.z = ax2 * r + bflo(sw.y);
    o.w = ax3 * r + bfhi(sw.y);
    *(float4*)(out + (size_t)node * 128 + sl * 4) = o;
  }
}

// ---------------- launch ----------------
extern "C" void kernel_launch(void* const* d_in, const int* in_sizes, int n_in,
                              void* d_out, int out_size, void* d_ws, size_t ws_size,
                              hipStream_t stream) {
  const void* x  = d_in[0];
  const int* ei  = (const int*)d_in[1];
  const void* Wg = d_in[2];
  const void* bg = d_in[3];
  const void* Wq = d_in[4];
  const void* bq = d_in[5];
  const void* Wk = d_in[6];
  const void* bk = d_in[7];
  const void* Wv = d_in[8];
  const void* bv = d_in[9];
  const void* Ws = d_in[10];
  const void* bs = d_in[11];
  float* out = (float*)d_out;

  const int N = in_sizes[0] / 128;
  const int E = in_sizes[1] / 2;
  int tilesM = (N + 15) / 16;
  int nscan = (N + 1023) / 1024;
  const int B = 256;

  // ---- workspace carve (256B aligned) ----
  char* ws = (char*)d_ws;
  size_t off = 0;
  auto carve = [&](size_t bytes) -> void* {
    void* p = ws + off;
    off += (bytes + 255) & ~(size_t)255;
    return p;
  };
  int* flag = (int*)carve(256);
  float* bias512 = (float*)carve(512 * 4);
  float* bgf = (float*)carve(128 * 4);
  float* dinv = (float*)carve((size_t)N * 4);
  int* cnt = (int*)carve((size_t)N * 4);
  int* rowptr = (int*)carve((size_t)(N + 1) * 4);
  int* chunkscan = (int*)carve((size_t)N * 4);
  int* partials = (int*)carve((size_t)(nscan + 1) * 4);
  int* srcs = (int*)carve((size_t)E * 4);
  int* erank = (int*)carve((size_t)E * 4);
  short* WpG = (short*)carve((size_t)16384 * 2);
  short* WpQ = (short*)carve((size_t)65536 * 2);
  short* h0bf = (short*)carve((size_t)N * 128 * 2);
  short* hbf = (short*)carve((size_t)N * 128 * 2);
  short* qb = (short*)carve((size_t)N * 128 * 2);
  short* kvb = (short*)carve((size_t)N * 256 * 2);  // interleaved k(f16)/v(bf16)
  short* skipb = (short*)carve((size_t)N * 128 * 2);

  int Gp = (10880 + B - 1) / B;          // prep blocks
  int Gh = (E + B - 1) / B;              // hist blocks
  int Gg = (tilesM * 64 + B - 1) / B;    // gemm_h0 blocks (4 waves each)
  int Gf = (E + B - 1) / B;              // fill blocks

  init_kernel<<<1 + (N + B - 1) / B, B, 0, stream>>>((const unsigned short*)x, flag, cnt, N);
  prep_hist<<<Gp + Gh, B, 0, stream>>>(bg, bq, bk, bv, bs, Wg, Wq, Wk, Wv, Ws, flag,
                                       bgf, bias512, WpG, WpQ, ei, cnt, erank, E, Gp);
  scanA<<<nscan, 1024, 0, stream>>>(cnt, chunkscan, partials, N);
  scanB<<<1, 64, 0, stream>>>(partials, nscan);
  scanC<<<(N + B - 1) / B, B, 0, stream>>>(cnt, chunkscan, partials, rowptr, dinv, N);
  gemmh0_fill<<<Gg + Gf, B, 0, stream>>>(x, flag, WpG, dinv, h0bf, N, ei, rowptr, erank,
                                         srcs, E, Gg);
  gcn_gather<<<(N + 7) / 8, B, 0, stream>>>(rowptr, srcs, dinv, (const unsigned*)h0bf, bgf,
                                            (unsigned*)hbf, N);
  gemm_qkvs<<<(tilesM * 4 + 3) / 4, B, 0, stream>>>(hbf, WpQ, bias512, qb, kvb, skipb, N);
  attn_fused<<<(N + 3) / 4, B, 0, stream>>>(rowptr, srcs, (const unsigned*)qb,
                                            (const unsigned*)kvb, (const unsigned*)skipb, out, N);
}

// Round 6
// 246.275 us; speedup vs baseline: 1.0706x; 1.0706x over previous
//
#include <hip/hip_runtime.h>
#include <hip/hip_bf16.h>

typedef __attribute__((ext_vector_type(8))) short short8;
typedef __attribute__((ext_vector_type(4))) float floatx4;
typedef _Float16 half2v __attribute__((ext_vector_type(2)));

// flag==1: inputs fp32 (proven R2->R3); flag==0: bf16.
__device__ __forceinline__ float ld_f(const void* p, int f32, int i) {
  if (f32) return ((const float*)p)[i];
  unsigned short u = ((const unsigned short*)p)[i];
  return __uint_as_float(((unsigned)u) << 16);
}
__device__ __forceinline__ short ld_bf(const void* p, int f32, int i) {
  if (!f32) return ((const short*)p)[i];
  __hip_bfloat16 h = __float2bfloat16(((const float*)p)[i]);
  return *reinterpret_cast<short*>(&h);
}
__device__ __forceinline__ unsigned short f_to_bfu(float v) {
  __hip_bfloat16 h = __float2bfloat16(v);
  return *reinterpret_cast<unsigned short*>(&h);
}
__device__ __forceinline__ short f_to_h(float v) {
  _Float16 h = (_Float16)v;
  return *reinterpret_cast<short*>(&h);
}
__device__ __forceinline__ float bflo(unsigned w) { return __uint_as_float(w << 16); }
__device__ __forceinline__ float bfhi(unsigned w) { return __uint_as_float(w & 0xFFFF0000u); }

// init: block 0 detects dtype; remaining blocks zero cnt.
__global__ void init_kernel(const unsigned short* __restrict__ xs, int* __restrict__ flag,
                            int* __restrict__ cnt, int N) {
  if (blockIdx.x == 0) {
    __shared__ int sbad;
    if (threadIdx.x == 0) sbad = 0;
    __syncthreads();
    int bad = 0;
    for (int j = 2 * threadIdx.x; j < 16384; j += 512) {  // EVEN u16 slots
      unsigned e = (xs[j] >> 7) & 0xFF;
      if (e >= 0xF0) bad = 1;
    }
    if (bad) atomicOr(&sbad, 1);
    __syncthreads();
    if (threadIdx.x == 0) flag[0] = sbad;
    return;
  }
  int i = (blockIdx.x - 1) * blockDim.x + threadIdx.x;
  if (i < N) cnt[i] = 0;
}

// prep (43 blocks: biases + weight packs) fused with hist (rest).
// hist records each edge's rank within its target (atomic return value),
// so the later CSR fill needs no atomics at all.
__global__ void prep_hist(const void* bg, const void* bq, const void* bk, const void* bv,
                          const void* bs, const void* Wg, const void* Wq, const void* Wk,
                          const void* Wv, const void* Ws, const int* __restrict__ flag,
                          float* __restrict__ bgf, float* __restrict__ bias512,
                          short* __restrict__ WpG, short* __restrict__ WpQ,
                          const int* __restrict__ ei, int* __restrict__ cnt,
                          int* __restrict__ erank, int E, int Gp) {
  if ((int)blockIdx.x >= Gp) {
    int e = (blockIdx.x - Gp) * blockDim.x + threadIdx.x;
    if (e < E) erank[e] = atomicAdd(&cnt[ei[E + e]], 1);
    return;
  }
  int tid = blockIdx.x * blockDim.x + threadIdx.x;
  int f = *flag;
  if (tid < 128) { bgf[tid] = ld_f(bg, f, tid); return; }
  if (tid < 640) {
    int t = tid - 128;
    const void* b = (t < 128) ? bq : (t < 256) ? bk : (t < 384) ? bv : bs;
    bias512[t] = ld_f(b, f, t & 127);
    return;
  }
  if (tid < 640 + 2048) {  // pack W_gcn
    int id = tid - 640;
    int lane = id & 63, kb = (id >> 6) & 3, tn = id >> 8;
    int k0 = kb * 32 + (lane >> 4) * 8;
    int n = tn * 16 + (lane & 15);
    short* dst = WpG + (size_t)id * 8;
#pragma unroll
    for (int j = 0; j < 8; ++j) dst[j] = ld_bf(Wg, f, (k0 + j) * 128 + n);
    return;
  }
  if (tid < 640 + 2048 + 8192) {  // pack Wq|Wk|Wv|Ws
    int id = tid - 640 - 2048;
    int lane = id & 63, kb = (id >> 6) & 3, tn = id >> 8;
    int k0 = kb * 32 + (lane >> 4) * 8;
    int n = tn * 16 + (lane & 15);
    const void* W = (n < 128) ? Wq : (n < 256) ? Wk : (n < 384) ? Wv : Ws;
    int col = n & 127;
    short* dst = WpQ + (size_t)id * 8;
#pragma unroll
    for (int j = 0; j < 8; ++j) dst[j] = ld_bf(W, f, (k0 + j) * 128 + col);
  }
}

__global__ void scanA(const int* __restrict__ cnt, int* __restrict__ chunkscan,
                      int* __restrict__ partials, int N) {
  __shared__ int sh[1024];
  int t = threadIdx.x;
  int g = blockIdx.x * 1024 + t;
  int v = (g < N) ? cnt[g] : 0;
  sh[t] = v;
  __syncthreads();
  for (int o = 1; o < 1024; o <<= 1) {
    int add = (t >= o) ? sh[t - o] : 0;
    __syncthreads();
    sh[t] += add;
    __syncthreads();
  }
  if (g < N) chunkscan[g] = sh[t];
  if (t == 1023) partials[blockIdx.x] = sh[1023];
}

// wave-parallel exclusive scan over partials (nb <= 64 fast path)
__global__ void scanB(int* __restrict__ partials, int nb) {
  int lane = threadIdx.x;
  if (nb <= 64) {
    int v = (lane < nb) ? partials[lane] : 0;
#pragma unroll
    for (int o = 1; o < 64; o <<= 1) {
      int t = __shfl_up(v, o);
      if (lane >= o) v += t;
    }
    int ex = __shfl_up(v, 1);
    if (lane == 0) ex = 0;
    if (lane < nb) partials[lane] = ex;
    return;
  }
  if (lane == 0) {
    int run = 0;
    for (int b = 0; b < nb; ++b) {
      int t = partials[b];
      partials[b] = run;
      run += t;
    }
  }
}

// rowptr + dinv fused
__global__ void scanC(const int* __restrict__ cnt, const int* __restrict__ chunkscan,
                      const int* __restrict__ partials, int* __restrict__ rowptr,
                      float* __restrict__ dinv, int N) {
  int g = blockIdx.x * blockDim.x + threadIdx.x;
  if (g == 0) rowptr[0] = 0;
  if (g >= N) return;
  int c = cnt[g];
  int inc = chunkscan[g] + partials[g >> 10];
  rowptr[g + 1] = inc;
  dinv[g] = rsqrtf((float)c + 1.0f);  // +1 self-loop
}

// ---- fused: MFMA GEMM h0' = (x @ W_gcn)*dinv[row] (bf16, pre-scaled) + CSR fill ----
// Fill is atomic-free: pos = rowptr[t] + erank[e] (rank captured during histogram).
__global__ void gemmh0_fill(const void* __restrict__ X, const int* __restrict__ flag,
                            const short* __restrict__ Bp, const float* __restrict__ dinv,
                            short* __restrict__ C, int M, const int* __restrict__ ei,
                            const int* __restrict__ rowptr, const int* __restrict__ erank,
                            int* __restrict__ srcs, int E, int Gg) {
  if ((int)blockIdx.x >= Gg) {
    int e = (blockIdx.x - Gg) * blockDim.x + threadIdx.x;
    if (e < E) {
      int t = ei[E + e];
      srcs[rowptr[t] + erank[e]] = ei[e];
    }
    return;
  }
  int wv = (blockIdx.x * blockDim.x + threadIdx.x) >> 6;
  int lane = threadIdx.x & 63;
  int tilesM = (M + 15) >> 4;
  if (wv >= tilesM) return;
  int f = *flag;
  int tm = wv;
  int m = tm * 16 + (lane & 15);
  int mc = m < M ? m : M - 1;
  int quad = lane >> 4;
  short8 a[4];
  if (f) {
    const float4* xr = (const float4*)((const float*)X + (size_t)mc * 128) + quad * 2;
#pragma unroll
    for (int kb = 0; kb < 4; ++kb) {
      float4 u = xr[kb * 8];
      float4 w = xr[kb * 8 + 1];
      a[kb][0] = (short)f_to_bfu(u.x);
      a[kb][1] = (short)f_to_bfu(u.y);
      a[kb][2] = (short)f_to_bfu(u.z);
      a[kb][3] = (short)f_to_bfu(u.w);
      a[kb][4] = (short)f_to_bfu(w.x);
      a[kb][5] = (short)f_to_bfu(w.y);
      a[kb][6] = (short)f_to_bfu(w.z);
      a[kb][7] = (short)f_to_bfu(w.w);
    }
  } else {
    const short* xr = (const short*)X + (size_t)mc * 128 + quad * 8;
#pragma unroll
    for (int kb = 0; kb < 4; ++kb) a[kb] = *(const short8*)(xr + kb * 32);
  }
  floatx4 acc[8];
#pragma unroll
  for (int tn = 0; tn < 8; ++tn) acc[tn] = (floatx4){0.f, 0.f, 0.f, 0.f};
#pragma unroll
  for (int kb = 0; kb < 4; ++kb) {
#pragma unroll
    for (int tn = 0; tn < 8; ++tn) {
      short8 b8 = *(const short8*)(Bp + ((size_t)(tn * 4 + kb) * 64 + lane) * 8);
      acc[tn] = __builtin_amdgcn_mfma_f32_16x16x32_bf16(a[kb], b8, acc[tn], 0, 0, 0);
    }
  }
  int row0 = tm * 16 + quad * 4;
  int cl = lane & 15;
  float dsc[4];
#pragma unroll
  for (int r = 0; r < 4; ++r) dsc[r] = (row0 + r < M) ? dinv[row0 + r] : 0.f;
#pragma unroll
  for (int tn = 0; tn < 8; ++tn)
#pragma unroll
    for (int r = 0; r < 4; ++r)
      if (row0 + r < M)
        C[(size_t)(row0 + r) * 128 + tn * 16 + cl] = (short)f_to_bfu(acc[tn][r] * dsc[r]);
}

// ---- FUSED: GCN aggregation (16 nodes -> LDS) + QKVS MFMA GEMM from LDS ----
// Phase 1 (8 waves, 2 nodes each): h = relu(dt*(sum h0'[s] + h0'[t]) + bg) into LDS.
// LDS row stride 136 shorts (272B = 17x16B): aligned for b128, rows land on banks
// 4*(r) mod 32 -> worst 2-way conflict (free).
// Phase 2 (8 waves): each wave computes 64 of the 512 output cols for the 16-row
// tile, A-fragments from LDS (no HBM h round-trip, no 4x A re-read).
__global__ __launch_bounds__(512) void gather_qkvs(
    const int* __restrict__ rowptr, const int* __restrict__ srcs,
    const float* __restrict__ dinv, const unsigned* __restrict__ h0,
    const float* __restrict__ bgf, const short* __restrict__ Bp,
    const float* __restrict__ bias512, short* __restrict__ qb,
    short* __restrict__ kvb, short* __restrict__ skipb, int N) {
  __shared__ short hsm[16][136];
  int tileBase = blockIdx.x * 16;
  int wv = threadIdx.x >> 6;  // 0..7
  int lane = threadIdx.x & 63;
  int hf = lane >> 5, q2 = (lane >> 4) & 1, sl = lane & 15, sl32 = lane & 31;
  int node = tileBase + wv * 2 + hf;
  int nodec = node < N ? node : N - 1;
  int beg = rowptr[nodec], end = rowptr[nodec + 1];
  int deg = node < N ? end - beg : 0;
  int dm1 = deg - 1;
  int dmc = dm1 > 0 ? dm1 : 0;
  int sreg = srcs[deg > 0 ? beg + (sl32 < dm1 ? sl32 : dm1) : 0];
  int degmax = deg;
  degmax = max(degmax, __shfl_xor(degmax, 32));
  int dd = degmax < 32 ? degmax : 32;
  int hb = hf << 5;
  float a0 = 0.f, a1 = 0.f, a2 = 0.f, a3 = 0.f, a4 = 0.f, a5 = 0.f, a6 = 0.f, a7 = 0.f;
  for (int base = 0; base < dd; base += 8) {
    int p0 = base + q2, p1 = p0 + 2, p2 = p0 + 4, p3 = p0 + 6;
    int s0 = __shfl(sreg, hb + (p0 < dmc ? p0 : dmc));
    int s1 = __shfl(sreg, hb + (p1 < dmc ? p1 : dmc));
    int s2 = __shfl(sreg, hb + (p2 < dmc ? p2 : dmc));
    int s3 = __shfl(sreg, hb + (p3 < dmc ? p3 : dmc));
    float m0 = p0 < deg ? 1.f : 0.f;
    float m1 = p1 < deg ? 1.f : 0.f;
    float m2 = p2 < deg ? 1.f : 0.f;
    float m3 = p3 < deg ? 1.f : 0.f;
    uint4 w0 = *(const uint4*)(h0 + (size_t)s0 * 64 + sl * 4);
    uint4 w1 = *(const uint4*)(h0 + (size_t)s1 * 64 + sl * 4);
    uint4 w2 = *(const uint4*)(h0 + (size_t)s2 * 64 + sl * 4);
    uint4 w3 = *(const uint4*)(h0 + (size_t)s3 * 64 + sl * 4);
    a0 += m0 * bflo(w0.x) + m1 * bflo(w1.x) + m2 * bflo(w2.x) + m3 * bflo(w3.x);
    a1 += m0 * bfhi(w0.x) + m1 * bfhi(w1.x) + m2 * bfhi(w2.x) + m3 * bfhi(w3.x);
    a2 += m0 * bflo(w0.y) + m1 * bflo(w1.y) + m2 * bflo(w2.y) + m3 * bflo(w3.y);
    a3 += m0 * bfhi(w0.y) + m1 * bfhi(w1.y) + m2 * bfhi(w2.y) + m3 * bfhi(w3.y);
    a4 += m0 * bflo(w0.z) + m1 * bflo(w1.z) + m2 * bflo(w2.z) + m3 * bflo(w3.z);
    a5 += m0 * bfhi(w0.z) + m1 * bfhi(w1.z) + m2 * bfhi(w2.z) + m3 * bfhi(w3.z);
    a6 += m0 * bflo(w0.w) + m1 * bflo(w1.w) + m2 * bflo(w2.w) + m3 * bflo(w3.w);
    a7 += m0 * bfhi(w0.w) + m1 * bfhi(w1.w) + m2 * bfhi(w2.w) + m3 * bfhi(w3.w);
  }
  for (int i = beg + 32 + q2; i < end; i += 2) {  // deg > 32: essentially never
    uint4 w0 = *(const uint4*)(h0 + (size_t)srcs[i] * 64 + sl * 4);
    a0 += bflo(w0.x);
    a1 += bfhi(w0.x);
    a2 += bflo(w0.y);
    a3 += bfhi(w0.y);
    a4 += bflo(w0.z);
    a5 += bfhi(w0.z);
    a6 += bflo(w0.w);
    a7 += bfhi(w0.w);
  }
  // combine the 2 quarters of this half
  a0 += __shfl_xor(a0, 16);
  a1 += __shfl_xor(a1, 16);
  a2 += __shfl_xor(a2, 16);
  a3 += __shfl_xor(a3, 16);
  a4 += __shfl_xor(a4, 16);
  a5 += __shfl_xor(a5, 16);
  a6 += __shfl_xor(a6, 16);
  a7 += __shfl_xor(a7, 16);
  if (q2 == 0) {
    // clamped reads keep out-of-range rows finite; their outputs are never stored
    uint4 hw = *(const uint4*)(h0 + (size_t)nodec * 64 + sl * 4);
    float dt = dinv[nodec];
    const float4* bb = (const float4*)bgf;
    float4 b0 = bb[sl * 2], b1 = bb[sl * 2 + 1];
    float v0 = (a0 + bflo(hw.x)) * dt + b0.x;
    float v1 = (a1 + bfhi(hw.x)) * dt + b0.y;
    float v2 = (a2 + bflo(hw.y)) * dt + b0.z;
    float v3 = (a3 + bfhi(hw.y)) * dt + b0.w;
    float v4 = (a4 + bflo(hw.z)) * dt + b1.x;
    float v5 = (a5 + bfhi(hw.z)) * dt + b1.y;
    float v6 = (a6 + bflo(hw.w)) * dt + b1.z;
    float v7 = (a7 + bfhi(hw.w)) * dt + b1.w;
    v0 = v0 > 0.f ? v0 : 0.f;
    v1 = v1 > 0.f ? v1 : 0.f;
    v2 = v2 > 0.f ? v2 : 0.f;
    v3 = v3 > 0.f ? v3 : 0.f;
    v4 = v4 > 0.f ? v4 : 0.f;
    v5 = v5 > 0.f ? v5 : 0.f;
    v6 = v6 > 0.f ? v6 : 0.f;
    v7 = v7 > 0.f ? v7 : 0.f;
    uint4 o;
    o.x = (unsigned)f_to_bfu(v0) | ((unsigned)f_to_bfu(v1) << 16);
    o.y = (unsigned)f_to_bfu(v2) | ((unsigned)f_to_bfu(v3) << 16);
    o.z = (unsigned)f_to_bfu(v4) | ((unsigned)f_to_bfu(v5) << 16);
    o.w = (unsigned)f_to_bfu(v6) | ((unsigned)f_to_bfu(v7) << 16);
    *(uint4*)(&hsm[wv * 2 + hf][sl * 8]) = o;
  }
  __syncthreads();
  // ---- phase 2: QKVS GEMM. Wave wv covers cols [wv*64, wv*64+64) of 512. ----
  int mrow = lane & 15;
  int quad = lane >> 4;
  short8 a[4];
#pragma unroll
  for (int kb = 0; kb < 4; ++kb)
    a[kb] = *(const short8*)(&hsm[mrow][quad * 8 + kb * 32]);
  floatx4 acc[4];
#pragma unroll
  for (int j = 0; j < 4; ++j) acc[j] = (floatx4){0.f, 0.f, 0.f, 0.f};
#pragma unroll
  for (int kb = 0; kb < 4; ++kb) {
#pragma unroll
    for (int j = 0; j < 4; ++j) {
      int tn = wv * 4 + j;
      short8 b8 = *(const short8*)(Bp + ((size_t)(tn * 4 + kb) * 64 + lane) * 8);
      acc[j] = __builtin_amdgcn_mfma_f32_16x16x32_bf16(a[kb], b8, acc[j], 0, 0, 0);
    }
  }
  int row0 = tileBase + quad * 4;
  int cl = lane & 15;
  int tng = wv >> 1;
#pragma unroll
  for (int j = 0; j < 4; ++j) {
    int cc = ((wv & 1) * 4 + j) * 16 + cl;
    float b = bias512[tng * 128 + cc];
#pragma unroll
    for (int r = 0; r < 4; ++r) {
      int row = row0 + r;
      if (row >= N) continue;
      float val = acc[j][r] + b;
      if (tng == 0) {
        qb[(size_t)row * 128 + cc] = f_to_h(val);
      } else if (tng == 3) {
        skipb[(size_t)row * 128 + cc] = (short)f_to_bfu(val);
      } else {
        size_t base = (size_t)row * 256 + (size_t)((cc >> 2) * 8 + (cc & 3));
        if (tng == 1)
          kvb[base] = f_to_h(val);               // k: f16
        else
          kvb[base + 4] = (short)f_to_bfu(val);  // v: bf16
      }
    }
  }
}

// ---- Fused attention: no-max softmax (dots ~N(0,1), exp-safe), f16 dot ----
// One node per wave; the 2 halves stagger slots (even/odd). Burst-8: 16 edges in
// flight per wave. Dot reduce is pure-VALU DPP. (Converged at ~47us / 3.7TB/s
// across 5 schedule variants -> per-CU miss-capacity bound; do not perturb.)
__device__ __forceinline__ float dpp_red8(float p) {
  p += __int_as_float(__builtin_amdgcn_mov_dpp(__float_as_int(p), 0xB1, 0xF, 0xF, true));
  p += __int_as_float(__builtin_amdgcn_mov_dpp(__float_as_int(p), 0x4E, 0xF, 0xF, true));
  p += __int_as_float(__builtin_amdgcn_mov_dpp(__float_as_int(p), 0x141, 0xF, 0xF, true));
  return p;
}
__device__ __forceinline__ float dot_dpp(half2v qa, half2v qc, unsigned kw0, unsigned kw1) {
  half2v k0 = *reinterpret_cast<half2v*>(&kw0);
  half2v k1 = *reinterpret_cast<half2v*>(&kw1);
#if __has_builtin(__builtin_amdgcn_fdot2)
  float p = __builtin_amdgcn_fdot2(qa, k0, 0.f, false);
  p = __builtin_amdgcn_fdot2(qc, k1, p, false);
#else
  float p = (float)qa[0] * (float)k0[0] + (float)qa[1] * (float)k0[1] +
            (float)qc[0] * (float)k1[0] + (float)qc[1] * (float)k1[1];
#endif
  return dpp_red8(p) * 0.17677669529663687f;  // 1/sqrt(32)
}

__global__ void attn_fused(const int* __restrict__ rowptr, const int* __restrict__ srcs,
                           const unsigned* __restrict__ qb, const unsigned* __restrict__ kvb,
                           const unsigned* __restrict__ skipb, float* __restrict__ out, int N) {
  int node = (int)((blockIdx.x * (long long)blockDim.x + threadIdx.x) >> 6);
  if (node >= N) return;
  int lane = threadIdx.x & 63;
  int hf = lane >> 5, sl = lane & 31;
  uint2 qw = *(const uint2*)(qb + (size_t)node * 64 + sl * 2);
  half2v qa = *reinterpret_cast<half2v*>(&qw.x);
  half2v qc = *reinterpret_cast<half2v*>(&qw.y);
  int beg = rowptr[node], end = rowptr[node + 1];
  int deg = end - beg;
  int dm1 = deg - 1;
  int dmc = dm1 > 0 ? dm1 : 0;
  int sreg = srcs[deg > 0 ? beg + (lane < dm1 ? lane : dm1) : 0];
  int dd = deg < 64 ? deg : 64;

  float denom = 0.f, ax0 = 0.f, ax1 = 0.f, ax2 = 0.f, ax3 = 0.f;
  for (int base = 0; base < dd; base += 16) {
    uint4 kv[8];
    int pp[8];
#pragma unroll
    for (int j = 0; j < 8; ++j) {
      int p = base + hf + 2 * j;  // half 0: even slots, half 1: odd slots
      pp[j] = p;
      int s = __shfl(sreg, p < dmc ? p : dmc);
      kv[j] = *(const uint4*)(kvb + (size_t)s * 128 + sl * 4);
    }
#pragma unroll
    for (int j = 0; j < 8; ++j) {
      float e = __expf(dot_dpp(qa, qc, kv[j].x, kv[j].y));
      e = pp[j] < deg ? e : 0.f;
      denom += e;
      ax0 += e * bflo(kv[j].z);
      ax1 += e * bfhi(kv[j].z);
      ax2 += e * bflo(kv[j].w);
      ax3 += e * bfhi(kv[j].w);
    }
  }
  for (int i = beg + 64 + hf; i < end; i += 2) {  // deg > 64: essentially never
    int s0 = srcs[i];
    uint4 kv0 = *(const uint4*)(kvb + (size_t)s0 * 128 + sl * 4);
    float e0 = __expf(dot_dpp(qa, qc, kv0.x, kv0.y));
    denom += e0;
    ax0 += e0 * bflo(kv0.z);
    ax1 += e0 * bfhi(kv0.z);
    ax2 += e0 * bflo(kv0.w);
    ax3 += e0 * bfhi(kv0.w);
  }
  // combine the two halves (all lanes active)
  denom += __shfl_xor(denom, 32);
  ax0 += __shfl_xor(ax0, 32);
  ax1 += __shfl_xor(ax1, 32);
  ax2 += __shfl_xor(ax2, 32);
  ax3 += __shfl_xor(ax3, 32);
  if (hf == 0) {
    float r = denom > 0.f ? 1.f / denom : 0.f;
    uint2 sw = *(const uint2*)(skipb + (size_t)node * 64 + sl * 2);
    float4 o;
    o.x = ax0 * r + bflo(sw.x);
    o.y = ax1 * r + bfhi(sw.x);
    o.z = ax2 * r + bflo(sw.y);
    o.w = ax3 * r + bfhi(sw.y);
    *(float4*)(out + (size_t)node * 128 + sl * 4) = o;
  }
}

// ---------------- launch ----------------
extern "C" void kernel_launch(void* const* d_in, const int* in_sizes, int n_in,
                              void* d_out, int out_size, void* d_ws, size_t ws_size,
                              hipStream_t stream) {
  const void* x  = d_in[0];
  const int* ei  = (const int*)d_in[1];
  const void* Wg = d_in[2];
  const void* bg = d_in[3];
  const void* Wq = d_in[4];
  const void* bq = d_in[5];
  const void* Wk = d_in[6];
  const void* bk = d_in[7];
  const void* Wv = d_in[8];
  const void* bv = d_in[9];
  const void* Ws = d_in[10];
  const void* bs = d_in[11];
  float* out = (float*)d_out;

  const int N = in_sizes[0] / 128;
  const int E = in_sizes[1] / 2;
  int tilesM = (N + 15) / 16;
  int nscan = (N + 1023) / 1024;
  const int B = 256;

  // ---- workspace carve (256B aligned) ----
  char* ws = (char*)d_ws;
  size_t off = 0;
  auto carve = [&](size_t bytes) -> void* {
    void* p = ws + off;
    off += (bytes + 255) & ~(size_t)255;
    return p;
  };
  int* flag = (int*)carve(256);
  float* bias512 = (float*)carve(512 * 4);
  float* bgf = (float*)carve(128 * 4);
  float* dinv = (float*)carve((size_t)N * 4);
  int* cnt = (int*)carve((size_t)N * 4);
  int* rowptr = (int*)carve((size_t)(N + 1) * 4);
  int* chunkscan = (int*)carve((size_t)N * 4);
  int* partials = (int*)carve((size_t)(nscan + 1) * 4);
  int* srcs = (int*)carve((size_t)E * 4);
  int* erank = (int*)carve((size_t)E * 4);
  short* WpG = (short*)carve((size_t)16384 * 2);
  short* WpQ = (short*)carve((size_t)65536 * 2);
  short* h0bf = (short*)carve((size_t)N * 128 * 2);
  short* qb = (short*)carve((size_t)N * 128 * 2);
  short* kvb = (short*)carve((size_t)N * 256 * 2);  // interleaved k(f16)/v(bf16)
  short* skipb = (short*)carve((size_t)N * 128 * 2);

  int Gp = (10880 + B - 1) / B;          // prep blocks
  int Gh = (E + B - 1) / B;              // hist blocks
  int Gg = (tilesM * 64 + B - 1) / B;    // gemm_h0 blocks (4 waves each)
  int Gf = (E + B - 1) / B;              // fill blocks

  init_kernel<<<1 + (N + B - 1) / B, B, 0, stream>>>((const unsigned short*)x, flag, cnt, N);
  prep_hist<<<Gp + Gh, B, 0, stream>>>(bg, bq, bk, bv, bs, Wg, Wq, Wk, Wv, Ws, flag,
                                       bgf, bias512, WpG, WpQ, ei, cnt, erank, E, Gp);
  scanA<<<nscan, 1024, 0, stream>>>(cnt, chunkscan, partials, N);
  scanB<<<1, 64, 0, stream>>>(partials, nscan);
  scanC<<<(N + B - 1) / B, B, 0, stream>>>(cnt, chunkscan, partials, rowptr, dinv, N);
  gemmh0_fill<<<Gg + Gf, B, 0, stream>>>(x, flag, WpG, dinv, h0bf, N, ei, rowptr, erank,
                                         srcs, E, Gg);
  gather_qkvs<<<tilesM, 512, 0, stream>>>(rowptr, srcs, dinv, (const unsigned*)h0bf, bgf,
                                          WpQ, bias512, qb, kvb, skipb, N);
  attn_fused<<<(N + 3) / 4, B, 0, stream>>>(rowptr, srcs, (const unsigned*)qb,
                                            (const unsigned*)kvb, (const unsigned*)skipb, out, N);
}